// Round 1
// baseline (240.422 us; speedup 1.0000x reference)
//
#include <hip/hip_runtime.h>
#include <math.h>

// Problem constants (AdaSpatialMLP): B=128, N=196, DIM=384, K=16, H=6, R=4
#define BB  128
#define NN  196
#define CDIM 384
#define KK  16
#define HH  6
#define DR  96    // DIM/R
#define HD  64    // DIM/H

typedef __attribute__((ext_vector_type(8))) short bf16x8;
typedef __attribute__((ext_vector_type(4))) float f32x4;

__device__ __forceinline__ unsigned short f2bf(float f) {
    unsigned u = __float_as_uint(f);
    u += 0x7FFFu + ((u >> 16) & 1u);   // RNE
    return (unsigned short)(u >> 16);
}
__device__ __forceinline__ unsigned pk2bf(float lo, float hi) {
    return (unsigned)f2bf(lo) | ((unsigned)f2bf(hi) << 16);
}

union AFrag { unsigned u[4]; bf16x8 f; };

// ---------------------------------------------------------------------------
// Prep: W1T[c][k] bf16 (96x384), W2T[c][k] bf16 (96x96), and
// wbT[n][m][k] bf16 (196x196x16, 1.2 MB) so A-form B-frags are one 16B load.
// ---------------------------------------------------------------------------
__global__ __launch_bounds__(256) void prep_kernel(
    const float* __restrict__ W1, const float* __restrict__ W2,
    const float* __restrict__ wb,
    unsigned short* __restrict__ W1T, unsigned short* __restrict__ W2T,
    unsigned short* __restrict__ wbT)
{
    const int bid = blockIdx.x;
    const int t   = threadIdx.x;
    if (bid < DR) {
        const int c = bid;     // 0..95
        for (int k = t; k < CDIM; k += 256)
            W1T[(size_t)c * CDIM + k] = f2bf(W1[(size_t)k * DR + c]);
        if (t < DR)
            W2T[(size_t)c * DR + t] = f2bf(W2[(size_t)t * DR + c]);
    } else {
        const int n = bid - DR;  // 0..195
        const int m = t;
        if (m < NN) {
            unsigned o[8];
            #pragma unroll
            for (int j = 0; j < 8; ++j) {
                const float a = wb[((size_t)(2 * j)     * NN + n) * NN + m];
                const float c = wb[((size_t)(2 * j + 1) * NN + n) * NN + m];
                o[j] = pk2bf(a, c);
            }
            unsigned* dst = (unsigned*)(wbT + ((size_t)n * NN + m) * KK);
            *(uint4*)dst       = make_uint4(o[0], o[1], o[2], o[3]);
            *(uint4*)(dst + 4) = make_uint4(o[4], o[5], o[6], o[7]);
        }
    }
}

// ---------------------------------------------------------------------------
// Stage 1 (MFMA): mix[row][h][k] bf16 = softmax_k( gelu(x@W1+b1) @ W2 + b2 )
// 1568 blocks x 128 thr (2 waves = 2 col-halves), 16 rows/block: twice the
// block-level diversity of the 32-row version, 2-wave barriers.
// ---------------------------------------------------------------------------
__global__ __launch_bounds__(128, 3) void adapter_kernel(
    const float* __restrict__ x,   const unsigned short* __restrict__ W1T,
    const float* __restrict__ b1,  const unsigned short* __restrict__ W2T,
    const float* __restrict__ b2,  unsigned short* __restrict__ mix_out)
{
    __shared__ unsigned short hidb[16][104];   // bf16, pitch 104 (208 B)

    const int t    = threadIdx.x;
    const int wc   = t >> 6;        // col half 0..1
    const int lane = t & 63;
    const int l15  = lane & 15;
    const int lq   = lane >> 4;
    const int row0 = blockIdx.x * 16;

    // ---- GEMM1: hid = gelu(x @ W1 + b1), rows l15, cols wc*48+ct*16+l15
    f32x4 acc[3];
    #pragma unroll
    for (int ct = 0; ct < 3; ++ct) {
        const float bj = b1[wc * 48 + ct * 16 + l15];
        acc[ct] = (f32x4){bj, bj, bj, bj};
    }
    const float* xrow = x + (size_t)(row0 + l15) * CDIM;
    for (int kc = 0; kc < CDIM; kc += 32) {
        const float4 u = *(const float4*)(xrow + kc + 8 * lq);
        const float4 v = *(const float4*)(xrow + kc + 8 * lq + 4);
        AFrag af;
        af.u[0] = pk2bf(u.x, u.y); af.u[1] = pk2bf(u.z, u.w);
        af.u[2] = pk2bf(v.x, v.y); af.u[3] = pk2bf(v.z, v.w);
        #pragma unroll
        for (int ct = 0; ct < 3; ++ct) {
            const bf16x8 bf = *(const bf16x8*)(W1T + (size_t)(wc * 48 + ct * 16 + l15) * CDIM + kc + 8 * lq);
            acc[ct] = __builtin_amdgcn_mfma_f32_16x16x32_bf16(af.f, bf, acc[ct], 0, 0, 0);
        }
    }
    // GELU (exact erf) -> hidb (C-layout: col=l15, row=lq*4+r)
    #pragma unroll
    for (int ct = 0; ct < 3; ++ct)
        #pragma unroll
        for (int r = 0; r < 4; ++r) {
            const float vv = acc[ct][r];
            hidb[lq * 4 + r][wc * 48 + ct * 16 + l15] =
                f2bf(0.5f * vv * (1.0f + erff(vv * 0.70710678118654752f)));
        }
    __syncthreads();

    // ---- GEMM2: logits = hid @ W2 + b2 ----
    f32x4 acc2[3];
    #pragma unroll
    for (int ct = 0; ct < 3; ++ct) {
        const float bj = b2[wc * 48 + ct * 16 + l15];
        acc2[ct] = (f32x4){bj, bj, bj, bj};
    }
    #pragma unroll
    for (int kc = 0; kc < DR; kc += 32) {
        const bf16x8 af = *(const bf16x8*)&hidb[l15][kc + 8 * lq];
        #pragma unroll
        for (int ct = 0; ct < 3; ++ct) {
            const bf16x8 bf = *(const bf16x8*)(W2T + (size_t)(wc * 48 + ct * 16 + l15) * DR + kc + 8 * lq);
            acc2[ct] = __builtin_amdgcn_mfma_f32_16x16x32_bf16(af, bf, acc2[ct], 0, 0, 0);
        }
    }
    __syncthreads();   // all hidb reads done; reuse as logits buffer

    #pragma unroll
    for (int ct = 0; ct < 3; ++ct)
        #pragma unroll
        for (int r = 0; r < 4; ++r)
            hidb[lq * 4 + r][wc * 48 + ct * 16 + l15] = f2bf(acc2[ct][r]);
    __syncthreads();

    // ---- softmax over k (col = k*6+h), write mix bf16 [row][h][16k] ----
    if (t < 96) {
        const int r = t / 6, h = t % 6;
        float lg[KK];
        float mx = -1e30f;
        #pragma unroll
        for (int k = 0; k < KK; ++k) {
            lg[k] = __uint_as_float((unsigned)hidb[r][6 * k + h] << 16);
            mx = fmaxf(mx, lg[k]);
        }
        float s = 0.f;
        #pragma unroll
        for (int k = 0; k < KK; ++k) { lg[k] = __expf(lg[k] - mx); s += lg[k]; }
        const float inv = 1.0f / s;
        unsigned o[8];
        #pragma unroll
        for (int jj = 0; jj < 8; ++jj)
            o[jj] = pk2bf(lg[2 * jj] * inv, lg[2 * jj + 1] * inv);
        unsigned* op = (unsigned*)(mix_out + ((size_t)(row0 + r) * HH + h) * KK);
        *(uint4*)op       = make_uint4(o[0], o[1], o[2], o[3]);
        *(uint4*)(op + 4) = make_uint4(o[4], o[5], o[6], o[7]);
    }
}

// ---------------------------------------------------------------------------
// Stage 2, MFMA: per (b, m-quarter, head-triple): out_h[m,c] = sum_n W_h^T[m,n] x_h[n,c]
// 1024 blocks x 192 thr (3 waves, wave = local head). LDS 30720 B ->
// 4 fully-resident blocks/CU. bid = sub*128 + b puts all 8 blocks of a b on
// one XCD (L2-shared x slice). A-form done with MFMA 16x16x32 (upper 16 k
// zero): A = mix rows (h), B = wbT[n][m][k] -> C[h][m], 2 barriers/chunk.
// ---------------------------------------------------------------------------
__global__ __launch_bounds__(192, 3) void mix_mfma_kernel(
    const float* __restrict__ x,  const unsigned short* __restrict__ mixb,
    const unsigned short* __restrict__ wbT, float* __restrict__ out)
{
    __shared__ unsigned short xT[192][40];    // [c_local][n] bf16, 15360 B
    __shared__ unsigned short Asb[3][64][40]; // [h_local][m][n] bf16, 15360 B

    const int t    = threadIdx.x;
    const int bid  = blockIdx.x;
    const int b    = bid & 127;       // bid%8 == b%8 -> same-b blocks share an XCD
    const int sub  = bid >> 7;        // 0..7
    const int q    = sub >> 1;        // m-quarter
    const int hp   = sub & 1;         // head triple
    const int m0   = q * 52;
    const int qvalid = (q == 3) ? 40 : 52;
    const int lw   = t >> 6;          // local head 0..2
    const int hbase = hp * 3;
    const int lane = t & 63;
    const int l15  = lane & 15;
    const int lq   = lane >> 4;
    const int c0   = hp * 192;        // channel slice of this head triple

    const bf16x8 z8 = {0, 0, 0, 0, 0, 0, 0, 0};
    const f32x4  cz = {0.f, 0.f, 0.f, 0.f};

    f32x4 acc[4][4];
    #pragma unroll
    for (int mt = 0; mt < 4; ++mt)
        #pragma unroll
        for (int ct = 0; ct < 4; ++ct) acc[mt][ct] = cz;

    for (int nc = 0; nc < 7; ++nc) {
        const int n0 = nc * 32;
        __syncthreads();   // previous chunk's MFMA reads done

        // ---- stage x -> xT bf16 transposed (only this triple's 192 channels)
        #pragma unroll
        for (int it = 0; it < 4; ++it) {
            const int task = t + 192 * it;      // 0..767
            const int p  = task & 15;           // n-pair 0..15
            const int cq = task >> 4;           // c-quad 0..47
            const int n  = n0 + 2 * p;
            float4 va = make_float4(0.f, 0.f, 0.f, 0.f);
            float4 vb = make_float4(0.f, 0.f, 0.f, 0.f);
            if (n < NN)     va = *(const float4*)(x + ((size_t)b * NN + n) * CDIM + c0 + 4 * cq);
            if (n + 1 < NN) vb = *(const float4*)(x + ((size_t)b * NN + n + 1) * CDIM + c0 + 4 * cq);
            *(unsigned*)&xT[4 * cq + 0][2 * p] = pk2bf(va.x, vb.x);
            *(unsigned*)&xT[4 * cq + 1][2 * p] = pk2bf(va.y, vb.y);
            *(unsigned*)&xT[4 * cq + 2][2 * p] = pk2bf(va.z, vb.z);
            *(unsigned*)&xT[4 * cq + 3][2 * p] = pk2bf(va.w, vb.w);
        }

        // ---- A-form via MFMA: per n, C[h][m] = sum_k mix[b,n,h,k]*wbT[n][m][k]
        for (int nl = lw; nl < 32; nl += 3) {
            const int n = n0 + nl;
            if (n < NN) {
                bf16x8 af = z8;      // A rows = h, k = 8*lq+j (k>=16 zero)
                if (l15 < HH && lq < 2)
                    af = *(const bf16x8*)(mixb + (((size_t)b * NN + n) * HH + l15) * KK + 8 * lq);
                #pragma unroll
                for (int mt = 0; mt < 4; ++mt) {
                    const int m = m0 + mt * 16 + l15;
                    bf16x8 bf = z8;  // B cols = m, k = 8*lq+j
                    if (lq < 2 && m < NN)
                        bf = *(const bf16x8*)(wbT + ((size_t)n * NN + m) * KK + 8 * lq);
                    const f32x4 c = __builtin_amdgcn_mfma_f32_16x16x32_bf16(af, bf, cz, 0, 0, 0);
                    #pragma unroll
                    for (int r = 0; r < 4; ++r) {
                        const int hh = lq * 4 + r;   // C row = h
                        if (hh >= hbase && hh < hbase + 3)
                            Asb[hh - hbase][mt * 16 + l15][nl] = f2bf(c[r]);
                    }
                }
            } else {
                #pragma unroll
                for (int mt = 0; mt < 4; ++mt)
                    #pragma unroll
                    for (int r = 0; r < 4; ++r) {
                        const int hh = lq * 4 + r;
                        if (hh >= hbase && hh < hbase + 3)
                            Asb[hh - hbase][mt * 16 + l15][nl] = 0;
                    }
            }
        }
        __syncthreads();

        // ---- main MFMA: 4 m-tiles x 4 c-tiles, K-chunk = 32 ----
        bf16x8 afr[4], bfr[4];
        #pragma unroll
        for (int mt = 0; mt < 4; ++mt)
            afr[mt] = *(const bf16x8*)&Asb[lw][mt * 16 + l15][8 * lq];
        #pragma unroll
        for (int ct = 0; ct < 4; ++ct)
            bfr[ct] = *(const bf16x8*)&xT[lw * 64 + ct * 16 + l15][8 * lq];
        #pragma unroll
        for (int mt = 0; mt < 4; ++mt)
            #pragma unroll
            for (int ct = 0; ct < 4; ++ct)
                acc[mt][ct] = __builtin_amdgcn_mfma_f32_16x16x32_bf16(
                    afr[mt], bfr[ct], acc[mt][ct], 0, 0, 0);
    }

    // ---- epilogue: C/D layout col=l15, row=lq*4+r ----
    const int h = hbase + lw;
    #pragma unroll
    for (int mt = 0; mt < 4; ++mt) {
        #pragma unroll
        for (int r = 0; r < 4; ++r) {
            const int ms = mt * 16 + lq * 4 + r;
            if (ms < qvalid) {
                float* op = out + ((size_t)b * NN + m0 + ms) * CDIM + h * HD + l15;
                #pragma unroll
                for (int ct = 0; ct < 4; ++ct)
                    op[ct * 16] = acc[mt][ct][r];
            }
        }
    }
}

extern "C" void kernel_launch(void* const* d_in, const int* in_sizes, int n_in,
                              void* d_out, int out_size, void* d_ws, size_t ws_size,
                              hipStream_t stream) {
    (void)in_sizes; (void)n_in; (void)out_size; (void)ws_size;
    const float* x  = (const float*)d_in[0];
    const float* W1 = (const float*)d_in[1];
    const float* b1 = (const float*)d_in[2];
    const float* W2 = (const float*)d_in[3];
    const float* b2 = (const float*)d_in[4];
    const float* wb = (const float*)d_in[5];
    float* out = (float*)d_out;

    unsigned short* mixbuf = (unsigned short*)d_ws;                   // 4,816,896 B
    unsigned short* w1t = (unsigned short*)((char*)d_ws + 4816896);   //    73,728 B
    unsigned short* w2t = (unsigned short*)((char*)d_ws + 4890624);   //    18,432 B
    unsigned short* wbt = (unsigned short*)((char*)d_ws + 4909056);   // 1,229,312 B

    prep_kernel<<<DR + NN, 256, 0, stream>>>(W1, W2, wb, w1t, w2t, wbt);
    adapter_kernel<<<(BB * NN) / 16, 128, 0, stream>>>(x, w1t, b1, w2t, b2, mixbuf);
    mix_mfma_kernel<<<8 * BB, 192, 0, stream>>>(x, mixbuf, wbt, out);
}

// Round 2
// 199.670 us; speedup vs baseline: 1.2041x; 1.2041x over previous
//
#include <hip/hip_runtime.h>
#include <math.h>

// Problem constants (AdaSpatialMLP): B=128, N=196, DIM=384, K=16, H=6, R=4
#define BB  128
#define NN  196
#define CDIM 384
#define KK  16
#define HH  6
#define DR  96    // DIM/R
#define HD  64    // DIM/H
#define MP  208   // padded M (13 x 16) for wbT / A
#define NCHUNK 7  // n chunks of 32 (224 padded n)
#define PLANE 6656  // 32*MP elems: h-plane stride within one (b,nc) slab of A

typedef __attribute__((ext_vector_type(8))) short bf16x8;
typedef __attribute__((ext_vector_type(4))) float f32x4;

__device__ __forceinline__ unsigned short f2bf(float f) {
    unsigned u = __float_as_uint(f);
    u += 0x7FFFu + ((u >> 16) & 1u);   // RNE
    return (unsigned short)(u >> 16);
}
__device__ __forceinline__ unsigned pk2bf(float lo, float hi) {
    return (unsigned)f2bf(lo) | ((unsigned)f2bf(hi) << 16);
}

union AFrag { unsigned u[4]; bf16x8 f; };

// ---------------------------------------------------------------------------
// Prep: W1T[c][k] bf16 (96x384), W2T[c][k] bf16 (96x96), and padded
// wbT[n(224)][m(208)][k16] bf16 so producer loads are unconditional 16B frags.
// Pad region is zero-filled (-> A=0 there, harmless).
// ---------------------------------------------------------------------------
__global__ __launch_bounds__(256) void prep_kernel(
    const float* __restrict__ W1, const float* __restrict__ W2,
    const float* __restrict__ wb,
    unsigned short* __restrict__ W1T, unsigned short* __restrict__ W2T,
    unsigned short* __restrict__ wbT)
{
    const int bid = blockIdx.x;
    const int t   = threadIdx.x;
    if (bid < DR) {
        const int c = bid;     // 0..95
        for (int k = t; k < CDIM; k += 256)
            W1T[(size_t)c * CDIM + k] = f2bf(W1[(size_t)k * DR + c]);
        if (t < DR)
            W2T[(size_t)c * DR + t] = f2bf(W2[(size_t)t * DR + c]);
    } else {
        const int n = bid - DR;  // 0..223
        const int m = t;
        if (m < MP) {
            unsigned o[8] = {0u, 0u, 0u, 0u, 0u, 0u, 0u, 0u};
            if (n < NN && m < NN) {
                #pragma unroll
                for (int j = 0; j < 8; ++j) {
                    const float a = wb[((size_t)(2 * j)     * NN + n) * NN + m];
                    const float c = wb[((size_t)(2 * j + 1) * NN + n) * NN + m];
                    o[j] = pk2bf(a, c);
                }
            }
            unsigned* dst = (unsigned*)(wbT + ((size_t)n * MP + m) * KK);
            *(uint4*)dst       = make_uint4(o[0], o[1], o[2], o[3]);
            *(uint4*)(dst + 4) = make_uint4(o[4], o[5], o[6], o[7]);
        }
    }
}

// ---------------------------------------------------------------------------
// Stage 1 (MFMA): mix[row][h][k] bf16 = softmax_k( gelu(x@W1+b1) @ W2 + b2 )
// 1568 blocks x 128 thr (2 waves = 2 col-halves), 16 rows/block. (unchanged)
// ---------------------------------------------------------------------------
__global__ __launch_bounds__(128, 3) void adapter_kernel(
    const float* __restrict__ x,   const unsigned short* __restrict__ W1T,
    const float* __restrict__ b1,  const unsigned short* __restrict__ W2T,
    const float* __restrict__ b2,  unsigned short* __restrict__ mix_out)
{
    __shared__ unsigned short hidb[16][104];   // bf16, pitch 104 (208 B)

    const int t    = threadIdx.x;
    const int wc   = t >> 6;        // col half 0..1
    const int lane = t & 63;
    const int l15  = lane & 15;
    const int lq   = lane >> 4;
    const int row0 = blockIdx.x * 16;

    // ---- GEMM1: hid = gelu(x @ W1 + b1), rows l15, cols wc*48+ct*16+l15
    f32x4 acc[3];
    #pragma unroll
    for (int ct = 0; ct < 3; ++ct) {
        const float bj = b1[wc * 48 + ct * 16 + l15];
        acc[ct] = (f32x4){bj, bj, bj, bj};
    }
    const float* xrow = x + (size_t)(row0 + l15) * CDIM;
    for (int kc = 0; kc < CDIM; kc += 32) {
        const float4 u = *(const float4*)(xrow + kc + 8 * lq);
        const float4 v = *(const float4*)(xrow + kc + 8 * lq + 4);
        AFrag af;
        af.u[0] = pk2bf(u.x, u.y); af.u[1] = pk2bf(u.z, u.w);
        af.u[2] = pk2bf(v.x, v.y); af.u[3] = pk2bf(v.z, v.w);
        #pragma unroll
        for (int ct = 0; ct < 3; ++ct) {
            const bf16x8 bf = *(const bf16x8*)(W1T + (size_t)(wc * 48 + ct * 16 + l15) * CDIM + kc + 8 * lq);
            acc[ct] = __builtin_amdgcn_mfma_f32_16x16x32_bf16(af.f, bf, acc[ct], 0, 0, 0);
        }
    }
    // GELU (exact erf) -> hidb (C-layout: col=l15, row=lq*4+r)
    #pragma unroll
    for (int ct = 0; ct < 3; ++ct)
        #pragma unroll
        for (int r = 0; r < 4; ++r) {
            const float vv = acc[ct][r];
            hidb[lq * 4 + r][wc * 48 + ct * 16 + l15] =
                f2bf(0.5f * vv * (1.0f + erff(vv * 0.70710678118654752f)));
        }
    __syncthreads();

    // ---- GEMM2: logits = hid @ W2 + b2 ----
    f32x4 acc2[3];
    #pragma unroll
    for (int ct = 0; ct < 3; ++ct) {
        const float bj = b2[wc * 48 + ct * 16 + l15];
        acc2[ct] = (f32x4){bj, bj, bj, bj};
    }
    #pragma unroll
    for (int kc = 0; kc < DR; kc += 32) {
        const bf16x8 af = *(const bf16x8*)&hidb[l15][kc + 8 * lq];
        #pragma unroll
        for (int ct = 0; ct < 3; ++ct) {
            const bf16x8 bf = *(const bf16x8*)(W2T + (size_t)(wc * 48 + ct * 16 + l15) * DR + kc + 8 * lq);
            acc2[ct] = __builtin_amdgcn_mfma_f32_16x16x32_bf16(af, bf, acc2[ct], 0, 0, 0);
        }
    }
    __syncthreads();   // all hidb reads done; reuse as logits buffer

    #pragma unroll
    for (int ct = 0; ct < 3; ++ct)
        #pragma unroll
        for (int r = 0; r < 4; ++r)
            hidb[lq * 4 + r][wc * 48 + ct * 16 + l15] = f2bf(acc2[ct][r]);
    __syncthreads();

    // ---- softmax over k (col = k*6+h), write mix bf16 [row][h][16k] ----
    if (t < 96) {
        const int r = t / 6, h = t % 6;
        float lg[KK];
        float mx = -1e30f;
        #pragma unroll
        for (int k = 0; k < KK; ++k) {
            lg[k] = __uint_as_float((unsigned)hidb[r][6 * k + h] << 16);
            mx = fmaxf(mx, lg[k]);
        }
        float s = 0.f;
        #pragma unroll
        for (int k = 0; k < KK; ++k) { lg[k] = __expf(lg[k] - mx); s += lg[k]; }
        const float inv = 1.0f / s;
        unsigned o[8];
        #pragma unroll
        for (int jj = 0; jj < 8; ++jj)
            o[jj] = pk2bf(lg[2 * jj] * inv, lg[2 * jj + 1] * inv);
        unsigned* op = (unsigned*)(mix_out + ((size_t)(row0 + r) * HH + h) * KK);
        *(uint4*)op       = make_uint4(o[0], o[1], o[2], o[3]);
        *(uint4*)(op + 4) = make_uint4(o[4], o[5], o[6], o[7]);
    }
}

// ---------------------------------------------------------------------------
// Producer: A[b][nc][h][n32][m208] bf16 = sum_k mix[b,n,h,k] * wb[k,n,m].
// 896 blocks (b, nc) x 256 thr (4 waves). Per n: one MFMA per 16-m block
// (A-operand rows = h, B cols = m, k = 16 of 32). No LDS, no barriers:
// latency hidden by TLP. Stores coalesced along m (2B x 16 lanes runs).
// Computed ONCE per (b,n,m,h) — no head-triple duplication.
// ---------------------------------------------------------------------------
__global__ __launch_bounds__(256, 3) void aform_kernel(
    const unsigned short* __restrict__ mixb,
    const unsigned short* __restrict__ wbT,
    unsigned short* __restrict__ A)
{
    const int t    = threadIdx.x;
    const int w    = t >> 6;
    const int lane = t & 63;
    const int l15  = lane & 15;
    const int lq   = lane >> 4;
    const int b    = blockIdx.x & 127;   // bid%8 == b%8 -> per-b L2 locality
    const int nc   = blockIdx.x >> 7;

    const bf16x8 z8 = {0, 0, 0, 0, 0, 0, 0, 0};
    const f32x4  cz = {0.f, 0.f, 0.f, 0.f};
    const size_t bc6 = ((size_t)b * NCHUNK + nc) * HH;

    for (int i = 0; i < 8; ++i) {
        const int nl = 4 * i + w;          // each wave: nl == w (mod 4)
        const int n  = nc * 32 + nl;       // < 224 (wbT padded)
        bf16x8 af = z8;                    // A rows = h, k = 8*lq+j (k>=16 zero)
        if (n < NN && l15 < HH && lq < 2)
            af = *(const bf16x8*)(mixb + (((size_t)b * NN + n) * HH + l15) * KK + 8 * lq);
        f32x4 c[13];
        #pragma unroll
        for (int mt = 0; mt < 13; ++mt) {
            bf16x8 bf = z8;                // B cols = m, k = 8*lq+j
            if (lq < 2)
                bf = *(const bf16x8*)(wbT + ((size_t)n * MP + mt * 16 + l15) * KK + 8 * lq);
            c[mt] = __builtin_amdgcn_mfma_f32_16x16x32_bf16(af, bf, cz, 0, 0, 0);
        }
        // C/D: col=l15 (m), row=lq*4+r (h). Valid h<6: lq<2 for r0/r1, lq==0 for r2/r3.
        if (lq < 2) {
            unsigned short* p0 = A + (bc6 + (size_t)(lq * 4)) * PLANE + (size_t)nl * MP + l15;
            #pragma unroll
            for (int mt = 0; mt < 13; ++mt) {
                p0[mt * 16]         = f2bf(c[mt][0]);    // h = 4*lq
                p0[mt * 16 + PLANE] = f2bf(c[mt][1]);    // h = 4*lq+1
            }
            if (lq == 0) {
                #pragma unroll
                for (int mt = 0; mt < 13; ++mt) {
                    p0[mt * 16 + 2 * PLANE] = f2bf(c[mt][2]);   // h = 2
                    p0[mt * 16 + 3 * PLANE] = f2bf(c[mt][3]);   // h = 3
                }
            }
        }
    }
}

// ---------------------------------------------------------------------------
// Consumer GEMM: per (b, m-quarter, head-triple): out_h[m,c] = sum_n A_h[m,n] x_h[n,c]
// 1024 blocks x 192 thr (3 waves, wave = local head). Per chunk the staging
// phase is a pure coalesced copy: A-slab 12KB (8 u64/thread) + xT transpose.
// A-frags read from LDS via conflict-free ds_read_u16 gathers.
// ---------------------------------------------------------------------------
__global__ __launch_bounds__(192, 3) void mix_gemm_kernel(
    const float* __restrict__ x, const unsigned short* __restrict__ Ab,
    float* __restrict__ out)
{
    __shared__ unsigned short xT[192][40];   // [c_local][n] bf16, 15360 B
    __shared__ unsigned short As[3][32][68]; // [h_local][n][m_local] bf16, 13056 B

    const int t    = threadIdx.x;
    const int bid  = blockIdx.x;
    const int b    = bid & 127;       // bid%8 == b%8 -> same-b blocks share an XCD
    const int sub  = bid >> 7;        // 0..7
    const int q    = sub >> 1;        // m-quarter
    const int hp   = sub & 1;         // head triple
    const int m0   = q * 52;
    const int qvalid = (q == 3) ? 40 : 52;
    const int lw   = t >> 6;          // local head 0..2
    const int hbase = hp * 3;
    const int lane = t & 63;
    const int l15  = lane & 15;
    const int lq   = lane >> 4;
    const int c0   = hp * 192;        // channel slice of this head triple

    const f32x4 cz = {0.f, 0.f, 0.f, 0.f};
    f32x4 acc[4][4];
    #pragma unroll
    for (int mt = 0; mt < 4; ++mt)
        #pragma unroll
        for (int ct = 0; ct < 4; ++ct) acc[mt][ct] = cz;

    for (int nc = 0; nc < NCHUNK; ++nc) {
        const int n0 = nc * 32;
        __syncthreads();   // previous chunk's MFMA reads done

        // ---- A-slab loads: 96 rows (3h x 32n) x 128B, coalesced u64 ----
        unsigned long long av[8];
        const size_t bc6 = ((size_t)b * NCHUNK + nc) * HH + hbase;
        #pragma unroll
        for (int i = 0; i < 8; ++i) {
            const int P = t + 192 * i;        // 0..1535
            const int row = P >> 4, p = P & 15;
            const int hl = row >> 5, n = row & 31;
            av[i] = *(const unsigned long long*)(
                Ab + (bc6 + hl) * PLANE + (size_t)n * MP + m0 + 4 * p);
        }

        // ---- stage x -> xT bf16 transposed (this triple's 192 channels) ----
        #pragma unroll
        for (int it = 0; it < 4; ++it) {
            const int task = t + 192 * it;      // 0..767
            const int p  = task & 15;           // n-pair 0..15
            const int cq = task >> 4;           // c-quad 0..47
            const int n  = n0 + 2 * p;
            float4 va = make_float4(0.f, 0.f, 0.f, 0.f);
            float4 vb = make_float4(0.f, 0.f, 0.f, 0.f);
            if (n < NN)     va = *(const float4*)(x + ((size_t)b * NN + n) * CDIM + c0 + 4 * cq);
            if (n + 1 < NN) vb = *(const float4*)(x + ((size_t)b * NN + n + 1) * CDIM + c0 + 4 * cq);
            *(unsigned*)&xT[4 * cq + 0][2 * p] = pk2bf(va.x, vb.x);
            *(unsigned*)&xT[4 * cq + 1][2 * p] = pk2bf(va.y, vb.y);
            *(unsigned*)&xT[4 * cq + 2][2 * p] = pk2bf(va.z, vb.z);
            *(unsigned*)&xT[4 * cq + 3][2 * p] = pk2bf(va.w, vb.w);
        }

        // ---- write A-slab to LDS (8B stores, conflict-free) ----
        #pragma unroll
        for (int i = 0; i < 8; ++i) {
            const int P = t + 192 * i;
            const int row = P >> 4, p = P & 15;
            *(unsigned long long*)&As[row >> 5][row & 31][4 * p] = av[i];
        }
        __syncthreads();

        // ---- A-frags via u16 gathers (transpose-on-read), then 16 MFMA ----
        bf16x8 afr[4], bfr[4];
        #pragma unroll
        for (int mt = 0; mt < 4; ++mt) {
            union { unsigned short s[8]; bf16x8 v; } u;
            #pragma unroll
            for (int j = 0; j < 8; ++j)
                u.s[j] = As[lw][8 * lq + j][mt * 16 + l15];
            afr[mt] = u.v;
        }
        #pragma unroll
        for (int ct = 0; ct < 4; ++ct)
            bfr[ct] = *(const bf16x8*)&xT[lw * 64 + ct * 16 + l15][8 * lq];
        #pragma unroll
        for (int mt = 0; mt < 4; ++mt)
            #pragma unroll
            for (int ct = 0; ct < 4; ++ct)
                acc[mt][ct] = __builtin_amdgcn_mfma_f32_16x16x32_bf16(
                    afr[mt], bfr[ct], acc[mt][ct], 0, 0, 0);
    }

    // ---- epilogue: C/D layout col=l15 (c), row=lq*4+r (m) ----
    const int h = hbase + lw;
    #pragma unroll
    for (int mt = 0; mt < 4; ++mt) {
        #pragma unroll
        for (int r = 0; r < 4; ++r) {
            const int ms = mt * 16 + lq * 4 + r;
            if (ms < qvalid) {
                float* op = out + ((size_t)b * NN + m0 + ms) * CDIM + h * HD + l15;
                #pragma unroll
                for (int ct = 0; ct < 4; ++ct)
                    op[ct * 16] = acc[mt][ct][r];
            }
        }
    }
}

// ---------------------------------------------------------------------------
// Fallback (small workspace): round-1 fused mix kernel, padded-wbT stride.
// ---------------------------------------------------------------------------
__global__ __launch_bounds__(192, 3) void mix_mfma_fb_kernel(
    const float* __restrict__ x,  const unsigned short* __restrict__ mixb,
    const unsigned short* __restrict__ wbT, float* __restrict__ out)
{
    __shared__ unsigned short xT[192][40];
    __shared__ unsigned short Asb[3][64][40];

    const int t    = threadIdx.x;
    const int bid  = blockIdx.x;
    const int b    = bid & 127;
    const int sub  = bid >> 7;
    const int q    = sub >> 1;
    const int hp   = sub & 1;
    const int m0   = q * 52;
    const int qvalid = (q == 3) ? 40 : 52;
    const int lw   = t >> 6;
    const int hbase = hp * 3;
    const int lane = t & 63;
    const int l15  = lane & 15;
    const int lq   = lane >> 4;
    const int c0   = hp * 192;

    const bf16x8 z8 = {0, 0, 0, 0, 0, 0, 0, 0};
    const f32x4  cz = {0.f, 0.f, 0.f, 0.f};

    f32x4 acc[4][4];
    #pragma unroll
    for (int mt = 0; mt < 4; ++mt)
        #pragma unroll
        for (int ct = 0; ct < 4; ++ct) acc[mt][ct] = cz;

    for (int nc = 0; nc < 7; ++nc) {
        const int n0 = nc * 32;
        __syncthreads();

        #pragma unroll
        for (int it = 0; it < 4; ++it) {
            const int task = t + 192 * it;
            const int p  = task & 15;
            const int cq = task >> 4;
            const int n  = n0 + 2 * p;
            float4 va = make_float4(0.f, 0.f, 0.f, 0.f);
            float4 vb = make_float4(0.f, 0.f, 0.f, 0.f);
            if (n < NN)     va = *(const float4*)(x + ((size_t)b * NN + n) * CDIM + c0 + 4 * cq);
            if (n + 1 < NN) vb = *(const float4*)(x + ((size_t)b * NN + n + 1) * CDIM + c0 + 4 * cq);
            *(unsigned*)&xT[4 * cq + 0][2 * p] = pk2bf(va.x, vb.x);
            *(unsigned*)&xT[4 * cq + 1][2 * p] = pk2bf(va.y, vb.y);
            *(unsigned*)&xT[4 * cq + 2][2 * p] = pk2bf(va.z, vb.z);
            *(unsigned*)&xT[4 * cq + 3][2 * p] = pk2bf(va.w, vb.w);
        }

        for (int nl = lw; nl < 32; nl += 3) {
            const int n = n0 + nl;
            if (n < NN) {
                bf16x8 af = z8;
                if (l15 < HH && lq < 2)
                    af = *(const bf16x8*)(mixb + (((size_t)b * NN + n) * HH + l15) * KK + 8 * lq);
                #pragma unroll
                for (int mt = 0; mt < 4; ++mt) {
                    const int m = m0 + mt * 16 + l15;
                    bf16x8 bf = z8;
                    if (lq < 2 && m < NN)
                        bf = *(const bf16x8*)(wbT + ((size_t)n * MP + m) * KK + 8 * lq);
                    const f32x4 c = __builtin_amdgcn_mfma_f32_16x16x32_bf16(af, bf, cz, 0, 0, 0);
                    #pragma unroll
                    for (int r = 0; r < 4; ++r) {
                        const int hh = lq * 4 + r;
                        if (hh >= hbase && hh < hbase + 3)
                            Asb[hh - hbase][mt * 16 + l15][nl] = f2bf(c[r]);
                    }
                }
            } else {
                #pragma unroll
                for (int mt = 0; mt < 4; ++mt)
                    #pragma unroll
                    for (int r = 0; r < 4; ++r) {
                        const int hh = lq * 4 + r;
                        if (hh >= hbase && hh < hbase + 3)
                            Asb[hh - hbase][mt * 16 + l15][nl] = 0;
                    }
            }
        }
        __syncthreads();

        bf16x8 afr[4], bfr[4];
        #pragma unroll
        for (int mt = 0; mt < 4; ++mt)
            afr[mt] = *(const bf16x8*)&Asb[lw][mt * 16 + l15][8 * lq];
        #pragma unroll
        for (int ct = 0; ct < 4; ++ct)
            bfr[ct] = *(const bf16x8*)&xT[lw * 64 + ct * 16 + l15][8 * lq];
        #pragma unroll
        for (int mt = 0; mt < 4; ++mt)
            #pragma unroll
            for (int ct = 0; ct < 4; ++ct)
                acc[mt][ct] = __builtin_amdgcn_mfma_f32_16x16x32_bf16(
                    afr[mt], bfr[ct], acc[mt][ct], 0, 0, 0);
    }

    const int h = hbase + lw;
    #pragma unroll
    for (int mt = 0; mt < 4; ++mt) {
        #pragma unroll
        for (int r = 0; r < 4; ++r) {
            const int ms = mt * 16 + lq * 4 + r;
            if (ms < qvalid) {
                float* op = out + ((size_t)b * NN + m0 + ms) * CDIM + h * HD + l15;
                #pragma unroll
                for (int ct = 0; ct < 4; ++ct)
                    op[ct * 16] = acc[mt][ct][r];
            }
        }
    }
}

extern "C" void kernel_launch(void* const* d_in, const int* in_sizes, int n_in,
                              void* d_out, int out_size, void* d_ws, size_t ws_size,
                              hipStream_t stream) {
    (void)in_sizes; (void)n_in; (void)out_size;
    const float* x  = (const float*)d_in[0];
    const float* W1 = (const float*)d_in[1];
    const float* b1 = (const float*)d_in[2];
    const float* W2 = (const float*)d_in[3];
    const float* b2 = (const float*)d_in[4];
    const float* wb = (const float*)d_in[5];
    float* out = (float*)d_out;

    // workspace layout
    const size_t MIXB_OFF = 0;                 // 4,816,896 B
    const size_t W1T_OFF  = 4816896;           //    73,728 B
    const size_t W2T_OFF  = 4890624;           //    18,432 B
    const size_t WBT_OFF  = 4909056;           // 1,490,944 B (224*208*16*2)
    const size_t A_OFF    = 6400000;           // 71,565,312 B (+1KB slack)
    const size_t NEED     = A_OFF + 71565312ull + 1024ull;

    unsigned short* mixbuf = (unsigned short*)((char*)d_ws + MIXB_OFF);
    unsigned short* w1t    = (unsigned short*)((char*)d_ws + W1T_OFF);
    unsigned short* w2t    = (unsigned short*)((char*)d_ws + W2T_OFF);
    unsigned short* wbt    = (unsigned short*)((char*)d_ws + WBT_OFF);

    prep_kernel<<<DR + 224, 256, 0, stream>>>(W1, W2, wb, w1t, w2t, wbt);
    adapter_kernel<<<(BB * NN) / 16, 128, 0, stream>>>(x, w1t, b1, w2t, b2, mixbuf);

    if (ws_size >= NEED) {
        unsigned short* Ab = (unsigned short*)((char*)d_ws + A_OFF);
        aform_kernel<<<BB * NCHUNK, 256, 0, stream>>>(mixbuf, wbt, Ab);
        mix_gemm_kernel<<<8 * BB, 192, 0, stream>>>(x, Ab, out);
    } else {
        mix_mfma_fb_kernel<<<8 * BB, 192, 0, stream>>>(x, mixbuf, wbt, out);
    }
}

// Round 3
// 191.119 us; speedup vs baseline: 1.2580x; 1.0447x over previous
//
#include <hip/hip_runtime.h>
#include <math.h>

// Problem constants (AdaSpatialMLP): B=128, N=196, DIM=384, K=16, H=6, R=4
#define BB  128
#define NN  196
#define CDIM 384
#define KK  16
#define HH  6
#define DR  96    // DIM/R
#define HD  64    // DIM/H
#define MP  208   // padded M (13 x 16) for wbT / A
#define NCHUNK 7  // n chunks of 32 (224 padded n)
#define PLANE 6656  // 32*MP elems: h-plane stride within one (b,nc) slab of A

typedef __attribute__((ext_vector_type(8))) short bf16x8;
typedef __attribute__((ext_vector_type(4))) float f32x4;

__device__ __forceinline__ unsigned short f2bf(float f) {
    unsigned u = __float_as_uint(f);
    u += 0x7FFFu + ((u >> 16) & 1u);   // RNE
    return (unsigned short)(u >> 16);
}
__device__ __forceinline__ unsigned pk2bf(float lo, float hi) {
    return (unsigned)f2bf(lo) | ((unsigned)f2bf(hi) << 16);
}

union AFrag { unsigned u[4]; bf16x8 f; };

// ---------------------------------------------------------------------------
// Prep: W1T[c][k] bf16 (96x384), W2T[c][k] bf16 (96x96), and padded
// wbT[n(224)][m(208)][k16] bf16 so producer loads are unconditional 16B frags.
// Pad region is zero-filled (-> A=0 there, harmless).
// ---------------------------------------------------------------------------
__global__ __launch_bounds__(256) void prep_kernel(
    const float* __restrict__ W1, const float* __restrict__ W2,
    const float* __restrict__ wb,
    unsigned short* __restrict__ W1T, unsigned short* __restrict__ W2T,
    unsigned short* __restrict__ wbT)
{
    const int bid = blockIdx.x;
    const int t   = threadIdx.x;
    if (bid < DR) {
        const int c = bid;     // 0..95
        for (int k = t; k < CDIM; k += 256)
            W1T[(size_t)c * CDIM + k] = f2bf(W1[(size_t)k * DR + c]);
        if (t < DR)
            W2T[(size_t)c * DR + t] = f2bf(W2[(size_t)t * DR + c]);
    } else {
        const int n = bid - DR;  // 0..223
        const int m = t;
        if (m < MP) {
            unsigned o[8] = {0u, 0u, 0u, 0u, 0u, 0u, 0u, 0u};
            if (n < NN && m < NN) {
                #pragma unroll
                for (int j = 0; j < 8; ++j) {
                    const float a = wb[((size_t)(2 * j)     * NN + n) * NN + m];
                    const float c = wb[((size_t)(2 * j + 1) * NN + n) * NN + m];
                    o[j] = pk2bf(a, c);
                }
            }
            unsigned* dst = (unsigned*)(wbT + ((size_t)n * MP + m) * KK);
            *(uint4*)dst       = make_uint4(o[0], o[1], o[2], o[3]);
            *(uint4*)(dst + 4) = make_uint4(o[4], o[5], o[6], o[7]);
        }
    }
}

// ---------------------------------------------------------------------------
// Fused adapter + A-form: one block per (b, nc). Phase 1 computes
// mix[n0..n0+31][h][k] (GEMM1 -> GELU -> GEMM2 -> softmax) entirely in LDS
// (14% duplicated GEMM1 work vs the standalone adapter; kills the mixbuf
// round-trip and one kernel boundary). Phase 2 is the A-form producer:
// A[b][nc][h][n32][m208] = sum_k mix * wbT, one MFMA per 16-m block,
// latency hidden by TLP (no barriers in phase 2).
// ---------------------------------------------------------------------------
__global__ __launch_bounds__(256, 3) void mixa_kernel(
    const float* __restrict__ x,  const unsigned short* __restrict__ W1T,
    const float* __restrict__ b1, const unsigned short* __restrict__ W2T,
    const float* __restrict__ b2, const unsigned short* __restrict__ wbT,
    unsigned short* __restrict__ A)
{
    __shared__ unsigned short hidb[32][104];   // 6656 B, pitch 104
    __shared__ unsigned short msc[32][96];     // [n][h*16+k] bf16, 6144 B

    const int t    = threadIdx.x;
    const int w    = t >> 6;        // wave 0..3
    const int wm   = w & 1;         // row half
    const int wc   = w >> 1;        // col half
    const int lane = t & 63;
    const int l15  = lane & 15;
    const int lq   = lane >> 4;
    const int b    = blockIdx.x & 127;   // bid%8 == b%8
    const int nc   = blockIdx.x >> 7;
    const int n0   = nc * 32;

    // ---- GEMM1: hid = gelu(x @ W1 + b1); rows wm*16+l15 (n-local), 96 cols
    f32x4 acc[3];
    #pragma unroll
    for (int ct = 0; ct < 3; ++ct) {
        const float bj = b1[wc * 48 + ct * 16 + l15];
        acc[ct] = (f32x4){bj, bj, bj, bj};
    }
    const int nrow = n0 + wm * 16 + l15;
    const bool rv  = (nrow < NN);
    const float* xrow = x + ((size_t)b * NN + nrow) * CDIM;
    for (int kc = 0; kc < CDIM; kc += 32) {
        float4 u = make_float4(0.f, 0.f, 0.f, 0.f);
        float4 v = make_float4(0.f, 0.f, 0.f, 0.f);
        if (rv) {
            u = *(const float4*)(xrow + kc + 8 * lq);
            v = *(const float4*)(xrow + kc + 8 * lq + 4);
        }
        AFrag af;
        af.u[0] = pk2bf(u.x, u.y); af.u[1] = pk2bf(u.z, u.w);
        af.u[2] = pk2bf(v.x, v.y); af.u[3] = pk2bf(v.z, v.w);
        #pragma unroll
        for (int ct = 0; ct < 3; ++ct) {
            const bf16x8 bf = *(const bf16x8*)(W1T + (size_t)(wc * 48 + ct * 16 + l15) * CDIM + kc + 8 * lq);
            acc[ct] = __builtin_amdgcn_mfma_f32_16x16x32_bf16(af.f, bf, acc[ct], 0, 0, 0);
        }
    }
    #pragma unroll
    for (int ct = 0; ct < 3; ++ct)
        #pragma unroll
        for (int r = 0; r < 4; ++r) {
            const float vv = acc[ct][r];
            hidb[wm * 16 + lq * 4 + r][wc * 48 + ct * 16 + l15] =
                f2bf(0.5f * vv * (1.0f + erff(vv * 0.70710678118654752f)));
        }
    __syncthreads();

    // ---- GEMM2: logits = hid @ W2 + b2 ----
    f32x4 acc2[3];
    #pragma unroll
    for (int ct = 0; ct < 3; ++ct) {
        const float bj = b2[wc * 48 + ct * 16 + l15];
        acc2[ct] = (f32x4){bj, bj, bj, bj};
    }
    #pragma unroll
    for (int kc = 0; kc < DR; kc += 32) {
        const bf16x8 af = *(const bf16x8*)&hidb[wm * 16 + l15][kc + 8 * lq];
        #pragma unroll
        for (int ct = 0; ct < 3; ++ct) {
            const bf16x8 bf = *(const bf16x8*)(W2T + (size_t)(wc * 48 + ct * 16 + l15) * DR + kc + 8 * lq);
            acc2[ct] = __builtin_amdgcn_mfma_f32_16x16x32_bf16(af, bf, acc2[ct], 0, 0, 0);
        }
    }
    __syncthreads();   // all hidb reads done; reuse as logits buffer

    #pragma unroll
    for (int ct = 0; ct < 3; ++ct)
        #pragma unroll
        for (int r = 0; r < 4; ++r)
            hidb[wm * 16 + lq * 4 + r][wc * 48 + ct * 16 + l15] = f2bf(acc2[ct][r]);
    __syncthreads();

    // ---- softmax over k (logit col = k*6+h) -> msc[n][h*16+k] bf16 ----
    if (t < 192) {
        const int r = t / 6, h = t - r * 6;
        float lg[KK];
        float mx = -1e30f;
        #pragma unroll
        for (int k = 0; k < KK; ++k) {
            lg[k] = __uint_as_float((unsigned)hidb[r][6 * k + h] << 16);
            mx = fmaxf(mx, lg[k]);
        }
        float s = 0.f;
        #pragma unroll
        for (int k = 0; k < KK; ++k) { lg[k] = __expf(lg[k] - mx); s += lg[k]; }
        const float inv = 1.0f / s;
        unsigned o[8];
        #pragma unroll
        for (int jj = 0; jj < 8; ++jj)
            o[jj] = pk2bf(lg[2 * jj] * inv, lg[2 * jj + 1] * inv);
        unsigned* op = (unsigned*)&msc[r][16 * h];
        *(uint4*)op       = make_uint4(o[0], o[1], o[2], o[3]);
        *(uint4*)(op + 4) = make_uint4(o[4], o[5], o[6], o[7]);
    }
    __syncthreads();

    // ---- Phase 2: A-form producer (no barriers; TLP hides wbT latency) ----
    const bf16x8 z8 = {0, 0, 0, 0, 0, 0, 0, 0};
    const f32x4  cz = {0.f, 0.f, 0.f, 0.f};
    const size_t bc6 = ((size_t)b * NCHUNK + nc) * HH;

    for (int i = 0; i < 8; ++i) {
        const int nl = 4 * i + w;
        const int n  = n0 + nl;            // < 224 (wbT padded, zero there)
        bf16x8 af = z8;                    // A rows = h, k = 8*lq+j (k>=16 zero)
        if (l15 < HH && lq < 2)
            af = *(const bf16x8*)&msc[nl][l15 * 16 + 8 * lq];
        f32x4 c[13];
        #pragma unroll
        for (int mt = 0; mt < 13; ++mt) {
            bf16x8 bf = z8;                // B cols = m, k = 8*lq+j
            if (lq < 2)
                bf = *(const bf16x8*)(wbT + ((size_t)n * MP + mt * 16 + l15) * KK + 8 * lq);
            c[mt] = __builtin_amdgcn_mfma_f32_16x16x32_bf16(af, bf, cz, 0, 0, 0);
        }
        // C/D: col=l15 (m), row=lq*4+r (h). Valid h<6.
        if (lq < 2) {
            unsigned short* p0 = A + (bc6 + (size_t)(lq * 4)) * PLANE + (size_t)nl * MP + l15;
            #pragma unroll
            for (int mt = 0; mt < 13; ++mt) {
                p0[mt * 16]         = f2bf(c[mt][0]);    // h = 4*lq
                p0[mt * 16 + PLANE] = f2bf(c[mt][1]);    // h = 4*lq+1
            }
            if (lq == 0) {
                #pragma unroll
                for (int mt = 0; mt < 13; ++mt) {
                    p0[mt * 16 + 2 * PLANE] = f2bf(c[mt][2]);   // h = 2
                    p0[mt * 16 + 3 * PLANE] = f2bf(c[mt][3]);   // h = 3
                }
            }
        }
    }
}

// ---------------------------------------------------------------------------
// Consumer GEMM: per (b, m-quarter, head-triple): out_h[m,c] = sum_n A_h[m,n] x_h[n,c]
// 1024 blocks x 192 thr (3 waves, wave = local head). A-stream double-buffered
// (T14): chunk n+1's global loads are issued BEFORE chunk n's MFMA phase, so
// HBM latency hides under compute. x loads stay inline (L2/L3-hot).
// ---------------------------------------------------------------------------
__global__ __launch_bounds__(192, 3) void mix_gemm_kernel(
    const float* __restrict__ x, const unsigned short* __restrict__ Ab,
    float* __restrict__ out)
{
    __shared__ unsigned short xT[192][40];   // [c_local][n] bf16, 15360 B
    __shared__ unsigned short As[3][32][68]; // [h_local][n][m_local] bf16, 13056 B

    const int t    = threadIdx.x;
    const int bid  = blockIdx.x;
    const int b    = bid & 127;       // bid%8 == b%8 -> same-b blocks share an XCD
    const int sub  = bid >> 7;        // 0..7
    const int q    = sub >> 1;        // m-quarter
    const int hp   = sub & 1;         // head triple
    const int m0   = q * 52;
    const int qvalid = (q == 3) ? 40 : 52;
    const int lw   = t >> 6;          // local head 0..2
    const int hbase = hp * 3;
    const int lane = t & 63;
    const int l15  = lane & 15;
    const int lq   = lane >> 4;
    const int c0   = hp * 192;        // channel slice of this head triple

    const f32x4 cz = {0.f, 0.f, 0.f, 0.f};
    f32x4 acc[4][4];
    #pragma unroll
    for (int mt = 0; mt < 4; ++mt)
        #pragma unroll
        for (int ct = 0; ct < 4; ++ct) acc[mt][ct] = cz;

    unsigned long long av[8];

    // ---- prologue: issue chunk-0 A-slab loads ----
    {
        const size_t bc6 = (size_t)b * NCHUNK * HH + hbase;
        #pragma unroll
        for (int i = 0; i < 8; ++i) {
            const int P = t + 192 * i;        // 0..1535
            const int row = P >> 4, p = P & 15;
            av[i] = *(const unsigned long long*)(
                Ab + (bc6 + (size_t)(row >> 5)) * PLANE + (size_t)(row & 31) * MP + m0 + 4 * p);
        }
    }

    for (int nc = 0; nc < NCHUNK; ++nc) {
        const int n0 = nc * 32;
        if (nc) __syncthreads();   // previous chunk's LDS reads done

        // ---- write A-slab regs -> LDS (8B stores, conflict-free) ----
        #pragma unroll
        for (int i = 0; i < 8; ++i) {
            const int P = t + 192 * i;
            const int row = P >> 4, p = P & 15;
            *(unsigned long long*)&As[row >> 5][row & 31][4 * p] = av[i];
        }

        // ---- stage x -> xT bf16 transposed (this triple's 192 channels) ----
        #pragma unroll
        for (int it = 0; it < 4; ++it) {
            const int task = t + 192 * it;      // 0..767
            const int p  = task & 15;           // n-pair 0..15
            const int cq = task >> 4;           // c-quad 0..47
            const int n  = n0 + 2 * p;
            float4 va = make_float4(0.f, 0.f, 0.f, 0.f);
            float4 vb = make_float4(0.f, 0.f, 0.f, 0.f);
            if (n < NN)     va = *(const float4*)(x + ((size_t)b * NN + n) * CDIM + c0 + 4 * cq);
            if (n + 1 < NN) vb = *(const float4*)(x + ((size_t)b * NN + n + 1) * CDIM + c0 + 4 * cq);
            *(unsigned*)&xT[4 * cq + 0][2 * p] = pk2bf(va.x, vb.x);
            *(unsigned*)&xT[4 * cq + 1][2 * p] = pk2bf(va.y, vb.y);
            *(unsigned*)&xT[4 * cq + 2][2 * p] = pk2bf(va.z, vb.z);
            *(unsigned*)&xT[4 * cq + 3][2 * p] = pk2bf(va.w, vb.w);
        }
        __syncthreads();

        // ---- issue next chunk's A loads BEFORE compute (latency overlap) ----
        if (nc + 1 < NCHUNK) {
            const size_t bc6 = ((size_t)b * NCHUNK + nc + 1) * HH + hbase;
            #pragma unroll
            for (int i = 0; i < 8; ++i) {
                const int P = t + 192 * i;
                const int row = P >> 4, p = P & 15;
                av[i] = *(const unsigned long long*)(
                    Ab + (bc6 + (size_t)(row >> 5)) * PLANE + (size_t)(row & 31) * MP + m0 + 4 * p);
            }
        }

        // ---- A-frags via u16 gathers (transpose-on-read), then 16 MFMA ----
        bf16x8 afr[4], bfr[4];
        #pragma unroll
        for (int mt = 0; mt < 4; ++mt) {
            union { unsigned short s[8]; bf16x8 v; } u;
            #pragma unroll
            for (int j = 0; j < 8; ++j)
                u.s[j] = As[lw][8 * lq + j][mt * 16 + l15];
            afr[mt] = u.v;
        }
        #pragma unroll
        for (int ct = 0; ct < 4; ++ct)
            bfr[ct] = *(const bf16x8*)&xT[lw * 64 + ct * 16 + l15][8 * lq];
        #pragma unroll
        for (int mt = 0; mt < 4; ++mt)
            #pragma unroll
            for (int ct = 0; ct < 4; ++ct)
                acc[mt][ct] = __builtin_amdgcn_mfma_f32_16x16x32_bf16(
                    afr[mt], bfr[ct], acc[mt][ct], 0, 0, 0);
    }

    // ---- epilogue: C/D layout col=l15 (c), row=lq*4+r (m) ----
    const int h = hbase + lw;
    #pragma unroll
    for (int mt = 0; mt < 4; ++mt) {
        #pragma unroll
        for (int r = 0; r < 4; ++r) {
            const int ms = mt * 16 + lq * 4 + r;
            if (ms < qvalid) {
                float* op = out + ((size_t)b * NN + m0 + ms) * CDIM + h * HD + l15;
                #pragma unroll
                for (int ct = 0; ct < 4; ++ct)
                    op[ct * 16] = acc[mt][ct][r];
            }
        }
    }
}

// ---------------------------------------------------------------------------
// Fallback path (small workspace): standalone adapter + fused mix kernel.
// ---------------------------------------------------------------------------
__global__ __launch_bounds__(128, 3) void adapter_kernel(
    const float* __restrict__ x,   const unsigned short* __restrict__ W1T,
    const float* __restrict__ b1,  const unsigned short* __restrict__ W2T,
    const float* __restrict__ b2,  unsigned short* __restrict__ mix_out)
{
    __shared__ unsigned short hidb[16][104];

    const int t    = threadIdx.x;
    const int wc   = t >> 6;
    const int lane = t & 63;
    const int l15  = lane & 15;
    const int lq   = lane >> 4;
    const int row0 = blockIdx.x * 16;

    f32x4 acc[3];
    #pragma unroll
    for (int ct = 0; ct < 3; ++ct) {
        const float bj = b1[wc * 48 + ct * 16 + l15];
        acc[ct] = (f32x4){bj, bj, bj, bj};
    }
    const float* xrow = x + (size_t)(row0 + l15) * CDIM;
    for (int kc = 0; kc < CDIM; kc += 32) {
        const float4 u = *(const float4*)(xrow + kc + 8 * lq);
        const float4 v = *(const float4*)(xrow + kc + 8 * lq + 4);
        AFrag af;
        af.u[0] = pk2bf(u.x, u.y); af.u[1] = pk2bf(u.z, u.w);
        af.u[2] = pk2bf(v.x, v.y); af.u[3] = pk2bf(v.z, v.w);
        #pragma unroll
        for (int ct = 0; ct < 3; ++ct) {
            const bf16x8 bf = *(const bf16x8*)(W1T + (size_t)(wc * 48 + ct * 16 + l15) * CDIM + kc + 8 * lq);
            acc[ct] = __builtin_amdgcn_mfma_f32_16x16x32_bf16(af.f, bf, acc[ct], 0, 0, 0);
        }
    }
    #pragma unroll
    for (int ct = 0; ct < 3; ++ct)
        #pragma unroll
        for (int r = 0; r < 4; ++r) {
            const float vv = acc[ct][r];
            hidb[lq * 4 + r][wc * 48 + ct * 16 + l15] =
                f2bf(0.5f * vv * (1.0f + erff(vv * 0.70710678118654752f)));
        }
    __syncthreads();

    f32x4 acc2[3];
    #pragma unroll
    for (int ct = 0; ct < 3; ++ct) {
        const float bj = b2[wc * 48 + ct * 16 + l15];
        acc2[ct] = (f32x4){bj, bj, bj, bj};
    }
    #pragma unroll
    for (int kc = 0; kc < DR; kc += 32) {
        const bf16x8 af = *(const bf16x8*)&hidb[l15][kc + 8 * lq];
        #pragma unroll
        for (int ct = 0; ct < 3; ++ct) {
            const bf16x8 bf = *(const bf16x8*)(W2T + (size_t)(wc * 48 + ct * 16 + l15) * DR + kc + 8 * lq);
            acc2[ct] = __builtin_amdgcn_mfma_f32_16x16x32_bf16(af, bf, acc2[ct], 0, 0, 0);
        }
    }
    __syncthreads();

    #pragma unroll
    for (int ct = 0; ct < 3; ++ct)
        #pragma unroll
        for (int r = 0; r < 4; ++r)
            hidb[lq * 4 + r][wc * 48 + ct * 16 + l15] = f2bf(acc2[ct][r]);
    __syncthreads();

    if (t < 96) {
        const int r = t / 6, h = t % 6;
        float lg[KK];
        float mx = -1e30f;
        #pragma unroll
        for (int k = 0; k < KK; ++k) {
            lg[k] = __uint_as_float((unsigned)hidb[r][6 * k + h] << 16);
            mx = fmaxf(mx, lg[k]);
        }
        float s = 0.f;
        #pragma unroll
        for (int k = 0; k < KK; ++k) { lg[k] = __expf(lg[k] - mx); s += lg[k]; }
        const float inv = 1.0f / s;
        unsigned o[8];
        #pragma unroll
        for (int jj = 0; jj < 8; ++jj)
            o[jj] = pk2bf(lg[2 * jj] * inv, lg[2 * jj + 1] * inv);
        unsigned* op = (unsigned*)(mix_out + ((size_t)(row0 + r) * HH + h) * KK);
        *(uint4*)op       = make_uint4(o[0], o[1], o[2], o[3]);
        *(uint4*)(op + 4) = make_uint4(o[4], o[5], o[6], o[7]);
    }
}

__global__ __launch_bounds__(192, 3) void mix_mfma_fb_kernel(
    const float* __restrict__ x,  const unsigned short* __restrict__ mixb,
    const unsigned short* __restrict__ wbT, float* __restrict__ out)
{
    __shared__ unsigned short xT[192][40];
    __shared__ unsigned short Asb[3][64][40];

    const int t    = threadIdx.x;
    const int bid  = blockIdx.x;
    const int b    = bid & 127;
    const int sub  = bid >> 7;
    const int q    = sub >> 1;
    const int hp   = sub & 1;
    const int m0   = q * 52;
    const int qvalid = (q == 3) ? 40 : 52;
    const int lw   = t >> 6;
    const int hbase = hp * 3;
    const int lane = t & 63;
    const int l15  = lane & 15;
    const int lq   = lane >> 4;
    const int c0   = hp * 192;

    const bf16x8 z8 = {0, 0, 0, 0, 0, 0, 0, 0};
    const f32x4  cz = {0.f, 0.f, 0.f, 0.f};

    f32x4 acc[4][4];
    #pragma unroll
    for (int mt = 0; mt < 4; ++mt)
        #pragma unroll
        for (int ct = 0; ct < 4; ++ct) acc[mt][ct] = cz;

    for (int nc = 0; nc < 7; ++nc) {
        const int n0 = nc * 32;
        __syncthreads();

        #pragma unroll
        for (int it = 0; it < 4; ++it) {
            const int task = t + 192 * it;
            const int p  = task & 15;
            const int cq = task >> 4;
            const int n  = n0 + 2 * p;
            float4 va = make_float4(0.f, 0.f, 0.f, 0.f);
            float4 vb = make_float4(0.f, 0.f, 0.f, 0.f);
            if (n < NN)     va = *(const float4*)(x + ((size_t)b * NN + n) * CDIM + c0 + 4 * cq);
            if (n + 1 < NN) vb = *(const float4*)(x + ((size_t)b * NN + n + 1) * CDIM + c0 + 4 * cq);
            *(unsigned*)&xT[4 * cq + 0][2 * p] = pk2bf(va.x, vb.x);
            *(unsigned*)&xT[4 * cq + 1][2 * p] = pk2bf(va.y, vb.y);
            *(unsigned*)&xT[4 * cq + 2][2 * p] = pk2bf(va.z, vb.z);
            *(unsigned*)&xT[4 * cq + 3][2 * p] = pk2bf(va.w, vb.w);
        }

        for (int nl = lw; nl < 32; nl += 3) {
            const int n = n0 + nl;
            if (n < NN) {
                bf16x8 af = z8;
                if (l15 < HH && lq < 2)
                    af = *(const bf16x8*)(mixb + (((size_t)b * NN + n) * HH + l15) * KK + 8 * lq);
                #pragma unroll
                for (int mt = 0; mt < 4; ++mt) {
                    const int m = m0 + mt * 16 + l15;
                    bf16x8 bf = z8;
                    if (lq < 2 && m < NN)
                        bf = *(const bf16x8*)(wbT + ((size_t)n * MP + m) * KK + 8 * lq);
                    const f32x4 c = __builtin_amdgcn_mfma_f32_16x16x32_bf16(af, bf, cz, 0, 0, 0);
                    #pragma unroll
                    for (int r = 0; r < 4; ++r) {
                        const int hh = lq * 4 + r;
                        if (hh >= hbase && hh < hbase + 3)
                            Asb[hh - hbase][mt * 16 + l15][nl] = f2bf(c[r]);
                    }
                }
            } else {
                #pragma unroll
                for (int mt = 0; mt < 4; ++mt)
                    #pragma unroll
                    for (int r = 0; r < 4; ++r) {
                        const int hh = lq * 4 + r;
                        if (hh >= hbase && hh < hbase + 3)
                            Asb[hh - hbase][mt * 16 + l15][nl] = 0;
                    }
            }
        }
        __syncthreads();

        bf16x8 afr[4], bfr[4];
        #pragma unroll
        for (int mt = 0; mt < 4; ++mt)
            afr[mt] = *(const bf16x8*)&Asb[lw][mt * 16 + l15][8 * lq];
        #pragma unroll
        for (int ct = 0; ct < 4; ++ct)
            bfr[ct] = *(const bf16x8*)&xT[lw * 64 + ct * 16 + l15][8 * lq];
        #pragma unroll
        for (int mt = 0; mt < 4; ++mt)
            #pragma unroll
            for (int ct = 0; ct < 4; ++ct)
                acc[mt][ct] = __builtin_amdgcn_mfma_f32_16x16x32_bf16(
                    afr[mt], bfr[ct], acc[mt][ct], 0, 0, 0);
    }

    const int h = hbase + lw;
    #pragma unroll
    for (int mt = 0; mt < 4; ++mt) {
        #pragma unroll
        for (int r = 0; r < 4; ++r) {
            const int ms = mt * 16 + lq * 4 + r;
            if (ms < qvalid) {
                float* op = out + ((size_t)b * NN + m0 + ms) * CDIM + h * HD + l15;
                #pragma unroll
                for (int ct = 0; ct < 4; ++ct)
                    op[ct * 16] = acc[mt][ct][r];
            }
        }
    }
}

extern "C" void kernel_launch(void* const* d_in, const int* in_sizes, int n_in,
                              void* d_out, int out_size, void* d_ws, size_t ws_size,
                              hipStream_t stream) {
    (void)in_sizes; (void)n_in; (void)out_size;
    const float* x  = (const float*)d_in[0];
    const float* W1 = (const float*)d_in[1];
    const float* b1 = (const float*)d_in[2];
    const float* W2 = (const float*)d_in[3];
    const float* b2 = (const float*)d_in[4];
    const float* wb = (const float*)d_in[5];
    float* out = (float*)d_out;

    // workspace layout
    const size_t W1T_OFF  = 0;                 //    73,728 B
    const size_t W2T_OFF  = 73728;             //    18,432 B
    const size_t WBT_OFF  = 92160;             // 1,490,944 B (224*208*16*2)
    const size_t A_OFF    = 1583104;           // 71,565,312 B (+1KB slack)
    const size_t NEED     = A_OFF + 71565312ull + 1024ull;

    unsigned short* w1t = (unsigned short*)((char*)d_ws + W1T_OFF);
    unsigned short* w2t = (unsigned short*)((char*)d_ws + W2T_OFF);
    unsigned short* wbt = (unsigned short*)((char*)d_ws + WBT_OFF);

    prep_kernel<<<DR + 224, 256, 0, stream>>>(W1, W2, wb, w1t, w2t, wbt);

    if (ws_size >= NEED) {
        unsigned short* Ab = (unsigned short*)((char*)d_ws + A_OFF);
        mixa_kernel<<<BB * NCHUNK, 256, 0, stream>>>(x, w1t, b1, w2t, b2, wbt, Ab);
        mix_gemm_kernel<<<8 * BB, 192, 0, stream>>>(x, Ab, out);
    } else {
        unsigned short* mixbuf = (unsigned short*)((char*)d_ws + A_OFF);  // reuse
        adapter_kernel<<<(BB * NN) / 16, 128, 0, stream>>>(x, w1t, b1, w2t, b2, mixbuf);
        mix_mfma_fb_kernel<<<8 * BB, 192, 0, stream>>>(x, mixbuf, wbt, out);
    }
}